// Round 7
// baseline (4531.371 us; speedup 1.0000x reference)
//
#include <hip/hip_runtime.h>

// PolicyAwareLSTM: 2-layer LSTM (4096 x 336, 32->64->32) + seq1-MHA (== two 32x32
// matmuls) + dense 32->64->24 head. fp32 throughout (no fp32 MFMA on CDNA4).
//
// R7 = R4 structure (best verified, 1884us; NT=512, 72 weights/thread, no spill)
// with phase1/phase2 LOOP INTERCHANGE: chunk-j-outer / row-inner.
// Rationale: across R2/R4/R6 the allocator parks loop-carried weights in AGPRs
// (VGPR_Count 64/64/128; R6's 256-budget attempt spilled to scratch instead).
// R4's measured VALU issue (~1180 instr/thread-step) exceeds the source count
// (~700) by ~480 ~= one v_accvgpr_read per weight USE (72 weights x 8 rows).
// Old order (r-outer, j-inner) touches every weight once per row -> 576
// copies/step. New order stages act into registers per 4-wide chunk (same 24
// ds_read_b128, batched) and uses each weight for all 8 rows consecutively ->
// ~72 copies/step. Per-accumulator FMA order (j ascending) is UNCHANGED ->
// bitwise-identical results. DS traffic / barriers / gates / head identical to R4.
// Live regs: acc 32 + areg 32 + chunk weights ~16 -> fits 128-VGPR budget.

#define B_TOTAL 4096
#define T_STEPS 336
#define NF      32     // input features
#define U1N     64     // layer-1 units
#define G1      256    // 4*U1N
#define U2N     32     // layer-2 units
#define G2      128    // 4*U2N
#define RROWS   8      // batch rows per block
#define NT      512    // threads per block
#define KH1     12     // L1 K-slice (8 k-groups x 12 = 96)
#define KG1     8
#define KH2     6      // L2 K-slice (16 k-groups x 6 = 96)
#define KG2     16

__device__ __forceinline__ float fast_sigmoid(float x) {
    return __fdividef(1.0f, 1.0f + __expf(-x));
}

__device__ __forceinline__ float fast_tanh(float x) {
    float ax = fabsf(x);
    float e  = __expf(-2.0f * ax);
    float r  = __fdividef(1.0f - e, 1.0f + e);
    return __builtin_copysignf(r, x);
}

__global__ __launch_bounds__(NT, 4) void lstm_fused(
    const float* __restrict__ x,
    const float* __restrict__ W1, const float* __restrict__ U1, const float* __restrict__ b1,
    const float* __restrict__ W2, const float* __restrict__ U2, const float* __restrict__ b2,
    const float* __restrict__ Wv, const float* __restrict__ bv,
    const float* __restrict__ Wo, const float* __restrict__ bo,
    const float* __restrict__ Wd1, const float* __restrict__ bd1,
    const float* __restrict__ Wd2, const float* __restrict__ bd2,
    float* __restrict__ out)
{
    __shared__ float act_sh[RROWS][128];       // [x(32) | h1(64) | h2(32)] per row, 4KB
    __shared__ float zp[RROWS * KG1 * G1];     // 64KB: L1/L2 partials (flat); head scratch

    const int tid = threadIdx.x;
    const int r0  = blockIdx.x * RROWS;

    // ---- thread roles
    const int ucol = tid & 63;                 // L1 unit (0..63)
    const int kg1  = tid >> 6;                 // L1 k-group (0..7)
    const int u2   = tid & 31;                 // L2 unit (0..31)
    const int kg2  = tid >> 5;                 // L2 k-group (0..15)
    const int g1r  = tid >> 6, g1u = tid & 63; // gate1 / d1 mapping (8r x 64u)
    const int g2r  = tid >> 5, g2u = tid & 31; // gate2 / x-park / head mapping (8r x 32u)

    // ---- weights: 4 gate-columns of one unit, K-sliced (coalesced in unit index)
    float4 w1w[KH1];
    #pragma unroll
    for (int j = 0; j < KH1; ++j) {
        const int kk = KH1 * kg1 + j;          // 0..95 over [x(32)|h1(64)]
        const float* row = (kk < NF) ? (W1 + kk * G1) : (U1 + (kk - NF) * G1);
        w1w[j] = make_float4(row[ucol], row[64 + ucol], row[128 + ucol], row[192 + ucol]);
    }
    float4 b1v = make_float4(0.f, 0.f, 0.f, 0.f);
    if (kg1 == 0)
        b1v = make_float4(b1[ucol], b1[64 + ucol], b1[128 + ucol], b1[192 + ucol]);

    float4 w2w[KH2];
    #pragma unroll
    for (int j = 0; j < KH2; ++j) {
        const int kk = KH2 * kg2 + j;          // 0..95 over [h1(64)|h2(32)]
        const float* row = (kk < U1N) ? (W2 + kk * G2) : (U2 + (kk - U1N) * G2);
        w2w[j] = make_float4(row[u2], row[32 + u2], row[64 + u2], row[96 + u2]);
    }
    float4 b2v = make_float4(0.f, 0.f, 0.f, 0.f);
    if (kg2 == 0)
        b2v = make_float4(b2[u2], b2[32 + u2], b2[64 + u2], b2[96 + u2]);

    // ---- init: zero act (x area overwritten below), zero cell states
    reinterpret_cast<float2*>(&act_sh[0][0])[tid] = make_float2(0.f, 0.f); // 1024 floats
    float c1 = 0.f, c2 = 0.f;

    const int xbase = (r0 + g2r) * (T_STEPS * NF) + g2u;   // x-park role: row g2r, feat g2u
    __syncthreads();
    if (tid < 256) act_sh[g2r][g2u] = x[xbase];            // x_0
    __syncthreads();

    for (int t = 0; t < T_STEPS; ++t) {
        // prefetch next x slice (issued early; parked after B1)
        float xnext = 0.f;
        if (tid < 256) {
            const int tn = (t + 1 < T_STEPS) ? (t + 1) : (T_STEPS - 1);
            xnext = x[xbase + tn * NF];
        }

        // ---- phase 1: z1 partials. Chunk-j-outer / row-inner: each weight float4
        // is used for all 8 rows consecutively (one AGPR->VGPR copy per use-burst).
        {
            const int ab = KH1 * kg1;          // 16B-aligned (48B multiples)
            float4 acc[RROWS];
            #pragma unroll
            for (int r = 0; r < RROWS; ++r) acc[r] = b1v;
            #pragma unroll
            for (int cch = 0; cch < 3; ++cch) {          // 3 chunks x 4 k = 12
                float4 areg[RROWS];
                #pragma unroll
                for (int r = 0; r < RROWS; ++r)
                    areg[r] = *reinterpret_cast<const float4*>(&act_sh[r][ab + 4 * cch]);
                #pragma unroll
                for (int j = 0; j < 4; ++j) {
                    const float4 w = w1w[cch * 4 + j];
                    #pragma unroll
                    for (int r = 0; r < RROWS; ++r) {
                        const float a = (j == 0) ? areg[r].x : (j == 1) ? areg[r].y
                                       : (j == 2) ? areg[r].z : areg[r].w;
                        acc[r].x = fmaf(a, w.x, acc[r].x);
                        acc[r].y = fmaf(a, w.y, acc[r].y);
                        acc[r].z = fmaf(a, w.z, acc[r].z);
                        acc[r].w = fmaf(a, w.w, acc[r].w);
                    }
                }
            }
            #pragma unroll
            for (int r = 0; r < RROWS; ++r)
                *reinterpret_cast<float4*>(&zp[(r * KG1 + kg1) * G1 + 4 * ucol]) = acc[r];
        }
        __syncthreads();  // B1: zp(L1) ready; act reads of phase1 done

        // ---- gate 1: thread = (row g1r, unit g1u); sum 8 k-group partials (float4 reads)
        {
            float4 z = make_float4(0.f, 0.f, 0.f, 0.f);
            #pragma unroll
            for (int k = 0; k < KG1; ++k) {
                const float4 p = *reinterpret_cast<const float4*>(&zp[(g1r * KG1 + k) * G1 + 4 * g1u]);
                z.x += p.x; z.y += p.y; z.z += p.z; z.w += p.w;
            }
            const float ig = fast_sigmoid(z.x);
            const float fg = fast_sigmoid(z.y);
            const float gg = fast_tanh(z.z);
            const float og = fast_sigmoid(z.w);
            c1 = fmaf(fg, c1, ig * gg);
            act_sh[g1r][NF + g1u] = og * fast_tanh(c1);     // h1_t
            if (tid < 256) act_sh[g2r][g2u] = xnext;        // park x_{t+1}
        }
        __syncthreads();  // B2: h1_t visible; zp(L1) reads done

        // ---- phase 2: z2 partials. Chunk-j-outer / row-inner (chunks of 2 k).
        {
            const int ab2 = NF + KH2 * kg2;    // 8B aligned
            float4 acc[RROWS];
            #pragma unroll
            for (int r = 0; r < RROWS; ++r) acc[r] = b2v;
            #pragma unroll
            for (int cch = 0; cch < 3; ++cch) {          // 3 chunks x 2 k = 6
                float2 areg[RROWS];
                #pragma unroll
                for (int r = 0; r < RROWS; ++r)
                    areg[r] = *reinterpret_cast<const float2*>(&act_sh[r][ab2 + 2 * cch]);
                #pragma unroll
                for (int j = 0; j < 2; ++j) {
                    const float4 w = w2w[cch * 2 + j];
                    #pragma unroll
                    for (int r = 0; r < RROWS; ++r) {
                        const float a = (j == 0) ? areg[r].x : areg[r].y;
                        acc[r].x = fmaf(a, w.x, acc[r].x);
                        acc[r].y = fmaf(a, w.y, acc[r].y);
                        acc[r].z = fmaf(a, w.z, acc[r].z);
                        acc[r].w = fmaf(a, w.w, acc[r].w);
                    }
                }
            }
            #pragma unroll
            for (int r = 0; r < RROWS; ++r)
                *reinterpret_cast<float4*>(&zp[(r * KG2 + kg2) * G2 + 4 * u2]) = acc[r];
        }
        __syncthreads();  // B3: zp(L2) ready; act reads of phase2 done

        // ---- gate 2: tid<256 = (row g2r, unit g2u); sum 16 k-group partials
        if (tid < 256) {
            float4 z = make_float4(0.f, 0.f, 0.f, 0.f);
            #pragma unroll
            for (int k = 0; k < KG2; ++k) {
                const float4 p = *reinterpret_cast<const float4*>(&zp[(g2r * KG2 + k) * G2 + 4 * g2u]);
                z.x += p.x; z.y += p.y; z.z += p.z; z.w += p.w;
            }
            const float ig = fast_sigmoid(z.x);
            const float fg = fast_sigmoid(z.y);
            const float gg = fast_tanh(z.z);
            const float og = fast_sigmoid(z.w);
            c2 = fmaf(fg, c2, ig * gg);
            act_sh[g2r][96 + g2u] = og * fast_tanh(c2);     // h2_t
        }
        __syncthreads();  // B4: zp free for next phase1; h2_t visible
    }

    // ---- head: v = h2@Wv+bv ; o = v@Wo+bo ; d1 = relu(o@Wd1+bd1) ; out = d1@Wd2+bd2
    {
        float* hb = &zp[0];                    // scratch: v[0..256), o[256..512), d1[512..1024)
        if (tid < 256) {
            float acc = bv[g2u];
            #pragma unroll
            for (int j = 0; j < 32; ++j) acc = fmaf(act_sh[g2r][96 + j], Wv[j * 32 + g2u], acc);
            hb[tid] = acc;                     // v[r][u]
        }
        __syncthreads();
        if (tid < 256) {
            float acc = bo[g2u];
            #pragma unroll
            for (int j = 0; j < 32; ++j) acc = fmaf(hb[g2r * 32 + j], Wo[j * 32 + g2u], acc);
            hb[256 + tid] = acc;               // o[r][u] (separate region; no hazard)
        }
        __syncthreads();
        {
            // d1: all 512 threads, (row g1r, col g1u)
            float acc = bd1[g1u];
            #pragma unroll
            for (int j = 0; j < 32; ++j) acc = fmaf(hb[256 + g1r * 32 + j], Wd1[j * 64 + g1u], acc);
            hb[512 + tid] = fmaxf(acc, 0.f);   // d1[r][c]
        }
        __syncthreads();
        if (tid < RROWS * 24) {
            const int rr = tid / 24, cc = tid - rr * 24;
            float acc = bd2[cc];
            #pragma unroll
            for (int j = 0; j < 64; ++j) acc = fmaf(hb[512 + rr * 64 + j], Wd2[j * 24 + cc], acc);
            out[(r0 + rr) * 24 + cc] = acc;
        }
    }
}

extern "C" void kernel_launch(void* const* d_in, const int* in_sizes, int n_in,
                              void* d_out, int out_size, void* d_ws, size_t ws_size,
                              hipStream_t stream) {
    const float* x   = (const float*)d_in[0];
    const float* W1  = (const float*)d_in[1];
    const float* U1  = (const float*)d_in[2];
    const float* b1  = (const float*)d_in[3];
    const float* W2  = (const float*)d_in[4];
    const float* U2  = (const float*)d_in[5];
    const float* b2  = (const float*)d_in[6];
    // d_in[7..10] = Wq, bq, Wk, bk — dead: softmax over a length-1 axis is identically 1
    const float* Wv  = (const float*)d_in[11];
    const float* bv  = (const float*)d_in[12];
    const float* Wo  = (const float*)d_in[13];
    const float* bo  = (const float*)d_in[14];
    const float* Wd1 = (const float*)d_in[15];
    const float* bd1 = (const float*)d_in[16];
    const float* Wd2 = (const float*)d_in[17];
    const float* bd2 = (const float*)d_in[18];
    float* outp = (float*)d_out;

    hipLaunchKernelGGL(lstm_fused, dim3(B_TOTAL / RROWS), dim3(NT), 0, stream,
                       x, W1, U1, b1, W2, U2, b2, Wv, bv, Wo, bo,
                       Wd1, bd1, Wd2, bd2, outp);
}

// Round 9
// 1950.977 us; speedup vs baseline: 2.3226x; 2.3226x over previous
//
#include <hip/hip_runtime.h>

// PolicyAwareLSTM: 2-layer LSTM (4096 x 336, 32->64->32) + seq1-MHA (== two 32x32
// matmuls) + dense 32->64->24 head. fp32 throughout (no fp32 MFMA on CDNA4).
//
// R9 = R8 resubmitted verbatim (R8 bench died in infra: "container failed twice",
// same signature as R5 which passed unchanged as R6; source re-audited clean --
// no divergent barriers, no OOB, aligned b128 stages, legal builtins).
//
// R8: DS-pipe de-load via wave-uniform act staging.
// Model: R4's 13.5K cy/step ~= 82 LDS instr/wave-step x 16 waves x ~10cy (DS ~97%
// busy; VALUBusy 70% is overlap). In R4, kg1 = tid>>6 = wave id -> each wave's
// act k-slice is WAVE-UNIFORM, yet was read with 24 per-lane broadcast b128/b64
// per phase. R8 stages the 96-float slice with ONE ds_read_b128 (24 chunks across
// lanes) and extracts via v_readlane (VALU->SGPR, constant lane); v_fma takes the
// SGPR operand directly. DS instr/wave-step 82 -> ~32. VALU +192 readlane -> VALU
// becomes the critical pipe at ~7.8K cy/SIMD-step (was DS 13K).
//  - L1 mapping unchanged (unit=tid&63, kg1=tid>>6): FP association = R4 bitwise.
//  - L2 remap for wave-uniform k: thread owns GATE-PAIR {2sub,2sub+1} (sub=
//    (tid>>5)&1) of unit u2=tid&31 over k-slice [12*wv,+12), wv=tid>>6. zp2
//    layout [r][w][4*u2+2*sub] float2 -> gate2 reads ONE b128 per w (4 gates).
//  - r-outer loops (R4's proven allocation shape; R7's j-outer/areg spilled).
//  - act rows padded to 132 floats: stage-read bank spread (row stride 528B =
//    4-bank rotation), all bases stay 16B-aligned.

#define B_TOTAL 4096
#define T_STEPS 336
#define NF      32     // input features
#define U1N     64     // layer-1 units
#define G1      256    // 4*U1N
#define U2N     32     // layer-2 units
#define G2      128    // 4*U2N
#define RROWS   8      // batch rows per block
#define NT      512    // threads per block
#define KG1     8      // L1 k-groups (12 k each)
#define APAD    132    // padded activation row stride

__device__ __forceinline__ float fast_sigmoid(float x) {
    return __fdividef(1.0f, 1.0f + __expf(-x));
}

__device__ __forceinline__ float fast_tanh(float x) {
    float ax = fabsf(x);
    float e  = __expf(-2.0f * ax);
    float r  = __fdividef(1.0f - e, 1.0f + e);
    return __builtin_copysignf(r, x);
}

// extract component c of a staged float4 from lane ln (c, ln literal after unroll)
__device__ __forceinline__ float rl_get(const float4& stg, int c, int ln) {
    const float v = (c == 0) ? stg.x : (c == 1) ? stg.y : (c == 2) ? stg.z : stg.w;
    return __int_as_float(__builtin_amdgcn_readlane(__float_as_int(v), ln));
}

__global__ __launch_bounds__(NT, 4) void lstm_fused(
    const float* __restrict__ x,
    const float* __restrict__ W1, const float* __restrict__ U1, const float* __restrict__ b1,
    const float* __restrict__ W2, const float* __restrict__ U2, const float* __restrict__ b2,
    const float* __restrict__ Wv, const float* __restrict__ bv,
    const float* __restrict__ Wo, const float* __restrict__ bo,
    const float* __restrict__ Wd1, const float* __restrict__ bd1,
    const float* __restrict__ Wd2, const float* __restrict__ bd2,
    float* __restrict__ out)
{
    __shared__ float act_sh[RROWS][APAD];      // [x(32) | h1(64) | h2(32)] (+pad)
    __shared__ float zp[RROWS * KG1 * G1];     // 64KB: L1 partials; L2 partials (sub-region); head scratch

    const int tid = threadIdx.x;
    const int r0  = blockIdx.x * RROWS;

    // ---- thread roles
    const int ucol = tid & 63;                 // L1 unit (0..63)
    const int wv   = tid >> 6;                 // wave id = L1 k-group = L2 k-group
    const int sub  = (tid >> 5) & 1;           // L2 gate-pair selector
    const int u2   = tid & 31;                 // L2 unit (0..31)
    const int g1r  = tid >> 6, g1u = tid & 63; // gate1 / d1 mapping (8r x 64u)
    const int pr   = tid >> 5, pu = tid & 31;  // gate2 / x-park / head mapping (8r x 32u)

    // ---- L1 weights: 4 gate-columns of one unit, k in [12*wv, +12)   (48 floats)
    float4 w1w[12];
    #pragma unroll
    for (int j = 0; j < 12; ++j) {
        const int kk = 12 * wv + j;            // over [x(32)|h1(64)]
        const float* row = (kk < NF) ? (W1 + kk * G1) : (U1 + (kk - NF) * G1);
        w1w[j] = make_float4(row[ucol], row[64 + ucol], row[128 + ucol], row[192 + ucol]);
    }
    float4 b1v = make_float4(0.f, 0.f, 0.f, 0.f);
    if (wv == 0)
        b1v = make_float4(b1[ucol], b1[64 + ucol], b1[128 + ucol], b1[192 + ucol]);

    // ---- L2 weights: gate-pair {2sub, 2sub+1} of unit u2, k in [12*wv, +12)  (24 floats)
    float2 w2w[12];
    #pragma unroll
    for (int j = 0; j < 12; ++j) {
        const int kk = 12 * wv + j;            // over [h1(64)|h2(32)]
        const float* row = (kk < U1N) ? (W2 + kk * G2) : (U2 + (kk - U1N) * G2);
        w2w[j] = make_float2(row[64 * sub + u2], row[64 * sub + 32 + u2]);
    }
    float2 b2p = make_float2(0.f, 0.f);
    if (wv == 0)
        b2p = make_float2(b2[64 * sub + u2], b2[64 * sub + 32 + u2]);

    // ---- stage-read pointers (chunk = lane for lanes 0..23; dup chunk 23 above)
    const int lane = tid & 63;
    const int ch   = (lane < 24) ? lane : 23;
    const int rc   = ch / 3, cc = ch % 3;      // row 0..7, 16B-chunk 0..2 within slice
    const float4* p1 = reinterpret_cast<const float4*>(&act_sh[rc][12 * wv + 4 * cc]);
    const float4* p2 = reinterpret_cast<const float4*>(&act_sh[rc][NF + 12 * wv + 4 * cc]);

    // ---- init: zero act, zero cell states
    for (int i = tid; i < RROWS * APAD; i += NT) (&act_sh[0][0])[i] = 0.0f;
    float c1 = 0.f, c2 = 0.f;

    const int xbase = (r0 + pr) * (T_STEPS * NF) + pu;     // x-park: row pr, feat pu
    __syncthreads();
    if (tid < 256) act_sh[pr][pu] = x[xbase];              // x_0
    __syncthreads();

    for (int t = 0; t < T_STEPS; ++t) {
        // prefetch next x slice (parked after B1)
        float xnext = 0.f;
        if (tid < 256) {
            const int tn = (t + 1 < T_STEPS) ? (t + 1) : (T_STEPS - 1);
            xnext = x[xbase + tn * NF];
        }

        // ---- phase 1: z1 partials. ONE staged b128/wave; act via readlane (SGPR).
        {
            const float4 stg = *p1;            // 24 chunks = 96 floats, wave-uniform slice
            #pragma unroll
            for (int r = 0; r < RROWS; ++r) {
                float4 acc = b1v;
                #pragma unroll
                for (int j = 0; j < 12; ++j) {
                    const float a = rl_get(stg, j & 3, 3 * r + (j >> 2));
                    acc.x = fmaf(a, w1w[j].x, acc.x);
                    acc.y = fmaf(a, w1w[j].y, acc.y);
                    acc.z = fmaf(a, w1w[j].z, acc.z);
                    acc.w = fmaf(a, w1w[j].w, acc.w);
                }
                *reinterpret_cast<float4*>(&zp[(r * KG1 + wv) * G1 + 4 * ucol]) = acc;
            }
        }
        __syncthreads();  // B1: zp(L1) ready; phase-1 act reads done

        // ---- gate 1: thread = (row g1r, unit g1u); sum 8 k-group partials
        {
            float4 z = make_float4(0.f, 0.f, 0.f, 0.f);
            #pragma unroll
            for (int k = 0; k < KG1; ++k) {
                const float4 p = *reinterpret_cast<const float4*>(&zp[(g1r * KG1 + k) * G1 + 4 * g1u]);
                z.x += p.x; z.y += p.y; z.z += p.z; z.w += p.w;
            }
            const float ig = fast_sigmoid(z.x);
            const float fg = fast_sigmoid(z.y);
            const float gg = fast_tanh(z.z);
            const float og = fast_sigmoid(z.w);
            c1 = fmaf(fg, c1, ig * gg);
            act_sh[g1r][NF + g1u] = og * fast_tanh(c1);     // h1_t
            if (tid < 256) act_sh[pr][pu] = xnext;          // park x_{t+1}
        }
        __syncthreads();  // B2: h1_t + x_{t+1} visible; zp(L1) reads done

        // ---- phase 2: z2 partials. Thread: gates {2sub,2sub+1} of u2, k [12wv,+12).
        {
            const float4 stg = *p2;            // 96 floats of [h1|h2] slice, wave-uniform
            #pragma unroll
            for (int r = 0; r < RROWS; ++r) {
                float2 acc = b2p;
                #pragma unroll
                for (int j = 0; j < 12; ++j) {
                    const float a = rl_get(stg, j & 3, 3 * r + (j >> 2));
                    acc.x = fmaf(a, w2w[j].x, acc.x);
                    acc.y = fmaf(a, w2w[j].y, acc.y);
                }
                // col = 4*u2 + 2*sub: unit-major, 4 gates contiguous per unit
                *reinterpret_cast<float2*>(&zp[(r * 8 + wv) * G2 + 4 * u2 + 2 * sub]) = acc;
            }
        }
        __syncthreads();  // B3: zp(L2) ready; phase-2 act reads done

        // ---- gate 2: tid<256 = (row pr, unit pu); sum 8 k-group partials (b128 each)
        if (tid < 256) {
            float4 z = make_float4(0.f, 0.f, 0.f, 0.f);
            #pragma unroll
            for (int k = 0; k < 8; ++k) {
                const float4 p = *reinterpret_cast<const float4*>(&zp[(pr * 8 + k) * G2 + 4 * pu]);
                z.x += p.x; z.y += p.y; z.z += p.z; z.w += p.w;
            }
            const float ig = fast_sigmoid(z.x);
            const float fg = fast_sigmoid(z.y);
            const float gg = fast_tanh(z.z);
            const float og = fast_sigmoid(z.w);
            c2 = fmaf(fg, c2, ig * gg);
            act_sh[pr][96 + pu] = og * fast_tanh(c2);       // h2_t
        }
        __syncthreads();  // B4: zp free for next phase1; h2_t visible
    }

    // ---- head: v = h2@Wv+bv ; o = v@Wo+bo ; d1 = relu(o@Wd1+bd1) ; out = d1@Wd2+bd2
    {
        float* hb = &zp[0];                    // scratch: v[0..256), o[256..512), d1[512..1024)
        if (tid < 256) {
            float acc = bv[pu];
            #pragma unroll
            for (int j = 0; j < 32; ++j) acc = fmaf(act_sh[pr][96 + j], Wv[j * 32 + pu], acc);
            hb[tid] = acc;                     // v[r][u]
        }
        __syncthreads();
        if (tid < 256) {
            float acc = bo[pu];
            #pragma unroll
            for (int j = 0; j < 32; ++j) acc = fmaf(hb[pr * 32 + j], Wo[j * 32 + pu], acc);
            hb[256 + tid] = acc;               // o[r][u] (separate region; no hazard)
        }
        __syncthreads();
        {
            // d1: all 512 threads, (row g1r, col g1u)
            float acc = bd1[g1u];
            #pragma unroll
            for (int j = 0; j < 32; ++j) acc = fmaf(hb[256 + g1r * 32 + j], Wd1[j * 64 + g1u], acc);
            hb[512 + tid] = fmaxf(acc, 0.f);   // d1[r][c]
        }
        __syncthreads();
        if (tid < RROWS * 24) {
            const int rr = tid / 24, cci = tid - rr * 24;
            float acc = bd2[cci];
            #pragma unroll
            for (int j = 0; j < 64; ++j) acc = fmaf(hb[512 + rr * 64 + j], Wd2[j * 24 + cci], acc);
            out[(r0 + rr) * 24 + cci] = acc;
        }
    }
}

extern "C" void kernel_launch(void* const* d_in, const int* in_sizes, int n_in,
                              void* d_out, int out_size, void* d_ws, size_t ws_size,
                              hipStream_t stream) {
    const float* x   = (const float*)d_in[0];
    const float* W1  = (const float*)d_in[1];
    const float* U1  = (const float*)d_in[2];
    const float* b1  = (const float*)d_in[3];
    const float* W2  = (const float*)d_in[4];
    const float* U2  = (const float*)d_in[5];
    const float* b2  = (const float*)d_in[6];
    // d_in[7..10] = Wq, bq, Wk, bk — dead: softmax over a length-1 axis is identically 1
    const float* Wv  = (const float*)d_in[11];
    const float* bv  = (const float*)d_in[12];
    const float* Wo  = (const float*)d_in[13];
    const float* bo  = (const float*)d_in[14];
    const float* Wd1 = (const float*)d_in[15];
    const float* bd1 = (const float*)d_in[16];
    const float* Wd2 = (const float*)d_in[17];
    const float* bd2 = (const float*)d_in[18];
    float* outp = (float*)d_out;

    hipLaunchKernelGGL(lstm_fused, dim3(B_TOTAL / RROWS), dim3(NT), 0, stream,
                       x, W1, U1, b1, W2, U2, b2, Wv, bv, Wo, bo,
                       Wd1, bd1, Wd2, bd2, outp);
}